// Round 4
// baseline (601.149 us; speedup 1.0000x reference)
//
#include <hip/hip_runtime.h>
#include <hip/hip_bf16.h>
#include <math.h>

using bf16 = __hip_bfloat16;
typedef __bf16 v8bf __attribute__((ext_vector_type(8)));
typedef float v4f __attribute__((ext_vector_type(4)));

#define B_ 4
#define L_ 4096
#define D_ 1024
#define M_ (B_*L_)
#define CCH 128
#define LCH (L_/CCH)
#define NF 3584   // fused N: Wpv(1024) | Wk(1024) | Wkv(1024) | Wb1(512)

__device__ __forceinline__ float bf2f(bf16 v){ return __bfloat162float(v); }
__device__ __forceinline__ bf16 f2bf(float v){ return __float2bfloat16(v); }
__device__ __forceinline__ float us2f(ushort u){ union{unsigned u32; float f;}c; c.u32=((unsigned)u)<<16; return c.f; }
__device__ __forceinline__ ushort f2us(float v){ bf16 h=__float2bfloat16(v); return *(ushort*)&h; }
__device__ __forceinline__ float h2f(ushort u){ union{ushort s; _Float16 h;}c; c.s=u; return (float)c.h; }
__device__ __forceinline__ ushort f2h(float v){ union{ushort s; _Float16 h;}c; c.h=(_Float16)v; return c.s; }

// async global->LDS, 16B per lane, dest = wave-uniform base + lane*16  [m97 pattern]
__device__ __forceinline__ void g2l16(const void* g, void* l){
  __builtin_amdgcn_global_load_lds(
    (const __attribute__((address_space(1))) unsigned int*)g,
    (__attribute__((address_space(3))) unsigned int*)l, 16, 0, 0);
}

// ---------------- zero a float region (ws is poisoned 0xAA each launch) ----------------
__global__ void k_zeroN(float* __restrict__ p, int n){
  int i = blockIdx.x*256 + threadIdx.x;
  if (i < n) p[i] = 0.0f;
}

// ---------------- x fp32 -> bf16 ----------------
__global__ void k_cvt(const float* __restrict__ in, bf16* __restrict__ out){
  int i = (blockIdx.x*256 + threadIdx.x)*4;
  float4 v = *(const float4*)(in + i);
  out[i]   = f2bf(v.x);
  out[i+1] = f2bf(v.y);
  out[i+2] = f2bf(v.z);
  out[i+3] = f2bf(v.w);
}

// ---------------- pos_phases fp32 -> fp16 ----------------
__global__ void k_cvt_pp(const float* __restrict__ in, ushort* __restrict__ out){
  int i = (blockIdx.x*256 + threadIdx.x)*4;
  float4 v = *(const float4*)(in + i);
  out[i]   = f2h(v.x);
  out[i+1] = f2h(v.y);
  out[i+2] = f2h(v.z);
  out[i+3] = f2h(v.w);
}

// ---------------- weight convert+transpose fp32 (R x C) -> bf16 (C x R) ----------------
__global__ void k_ctr(const float* __restrict__ in, bf16* __restrict__ out, int R, int C){
  __shared__ float tile[32][33];
  int c0 = blockIdx.x*32, r0 = blockIdx.y*32;
  #pragma unroll
  for (int i=0;i<32;i+=8)
    tile[threadIdx.y+i][threadIdx.x] = in[(size_t)(r0+threadIdx.y+i)*C + c0+threadIdx.x];
  __syncthreads();
  #pragma unroll
  for (int i=0;i<32;i+=8)
    out[(size_t)(c0+threadIdx.y+i)*R + r0+threadIdx.x] = f2bf(tile[threadIdx.x][threadIdx.y+i]);
}

// ---------------- pack fused bias [bpv|bk|bkv|bb1] ----------------
__global__ void k_pack_bias(const float* __restrict__ bpv, const float* __restrict__ bk,
                            const float* __restrict__ bkv, const float* __restrict__ bb1,
                            float* __restrict__ bf){
  int i = blockIdx.x*256 + threadIdx.x;
  float v;
  if (i < 1024) v = bpv[i];
  else if (i < 2048) v = bk[i-1024];
  else if (i < 3072) v = bkv[i-2048];
  else v = bb1[i-3072];
  bf[i] = v;
}

__device__ __forceinline__ float geluf(float v){
  return 0.5f*v*(1.0f + erff(v*0.70710678118654752f));
}
__device__ __forceinline__ float fast_tanh(float v){
  float a = fabsf(v);
  float e = __expf(-2.0f*a);
  float t = (1.0f - e)/(1.0f + e);
  return copysignf(t, v);
}

// ---------------- MFMA GEMM: 256x256 tile, BK=64, 8 waves, 8-phase dbuf schedule ----------------
// m201-style schedule, 4 phases per K-tile (see R1 notes). This round adds:
// T1 chunked XCD swizzle: flat block id remapped so each XCD owns 8 contiguous
//   bm-panels x all bn -> A-panel stays in the owning XCD's L2 (nwg % 8 == 0 in
//   all three launches -> bijective).
// LDS T2 swizzle: linear LDS dest (g2l16 requirement), global SOURCE col pre-swizzled by
//   (sseg^srow), ds_read col XORed by (row&7)<<4  -> bank-conflict-free (verified 0 in R2).
// T5: setprio(1) around each 16-MFMA cluster.
#define BM 256
#define BN 256
#define BK 64

template<int EPI, bool CONCAT>
__global__ __launch_bounds__(512) void k_gemm(
    const bf16* __restrict__ A, int lda,
    const bf16* __restrict__ Bt, int ldb,
    const float* __restrict__ bias,
    const bf16* __restrict__ zeros,
    bf16* __restrict__ o_pv, ushort* __restrict__ o_kp, bf16* __restrict__ o_kv,
    const float* __restrict__ Wv2, const float* __restrict__ Wb2f,
    float* __restrict__ gaccp, float* __restrict__ bwaccp,
    float* __restrict__ outf, const float* __restrict__ residf,
    int N, int Ktot)
{
  __shared__ __align__(16) ushort As[2*BM*BK];
  __shared__ __align__(16) ushort Bs[2*BN*BK];
  int tid = threadIdx.x;
  int lane = tid & 63, wave = tid >> 6;      // 8 waves
  int wm = wave >> 2, wn = wave & 3;         // 2 (M) x 4 (N) wave grid
  // T1: chunked XCD-aware block swizzle (nwg % 8 == 0 for all launches)
  int nwgx = gridDim.x;
  int flat = blockIdx.y * nwgx + blockIdx.x;
  int chunk = (nwgx * gridDim.y) >> 3;
  int newid = (flat & 7) * chunk + (flat >> 3);
  int bn = (newid % nwgx) * BN, bm = (newid / nwgx) * BM;

  v4f zero = {0.f,0.f,0.f,0.f};
  v4f acc[8][4];
  #pragma unroll
  for (int i=0;i<8;i++)
    #pragma unroll
    for (int j=0;j<4;j++) acc[i][j] = zero;

  int mr = lane & 15, g4 = lane >> 4;        // MFMA fragment addressing
  int srow = lane >> 3, sseg = lane & 7;     // staging: 8 rows x 8 k-segments per wave
  int swzs = (sseg ^ srow) * 8;              // pre-swizzled source col (elements)

  // stage one half-tile of K-tile t into buffer t&1.
  // which: 0=A rows 0-127, 1=B rows 0-127, 2=B rows 128-255, 3=A rows 128-255
  auto stage_half = [&](int t, int which){
    int buf = t & 1;
    int kk = t * BK;
    bool isA = (which==0) || (which==3);
    int rbase = (which==0 || which==1) ? 0 : 128;
    ushort* dst = (isA ? As : Bs) + buf*(BM*BK);
    #pragma unroll
    for (int p=0;p<2;p++){
      int r = rbase + p*64 + wave*8 + srow;
      const bf16* src;
      if (isA){
        if (!CONCAT || kk < D_) {
          src = A + (size_t)(bm + r)*lda + (size_t)kk + swzs;
        } else {
          int m = bm + r;
          int l = m & (L_-1);
          src = (l==0) ? (zeros + swzs)
                       : (A + (size_t)(m-1)*lda + (size_t)(kk - D_) + swzs);
        }
      } else {
        src = Bt + (size_t)(bn + r)*ldb + (size_t)kk + swzs;
      }
      g2l16(src, dst + (size_t)(rbase + p*64 + wave*8)*BK);
    }
  };

  // swizzled LDS fragment reads
  auto lds_a = [&](const ushort* Ab, int ih, int i, int ks)->v8bf{
    int row = ih*128 + wm*64 + i*16 + mr;
    int off = row*128 + ((ks*64 + g4*16) ^ ((mr&7)<<4));
    return *(const v8bf*)((const char*)Ab + off);
  };
  auto lds_b = [&](const ushort* Bb, int jh, int j, int ks)->v8bf{
    int row = jh*128 + wn*32 + j*16 + mr;
    int off = row*128 + ((ks*64 + g4*16) ^ ((mr&7)<<4));
    return *(const v8bf*)((const char*)Bb + off);
  };

  int nt = Ktot / BK;
  // prologue: stage all 4 half-tiles of tile 0; require Ah0,Bh0 resident
  stage_half(0,0); stage_half(0,1); stage_half(0,2); stage_half(0,3);
  asm volatile("s_waitcnt vmcnt(4)" ::: "memory");
  asm volatile("s_barrier" ::: "memory");

  v8bf a[4][2];       // current ih's A fragments [i][ks]
  v8bf b[2][2][2];    // both B halves [jh][j][ks]

  for (int t=0; t<nt; ++t){
    const ushort* Ab = As + (t&1)*(BM*BK);
    const ushort* Bb = Bs + (t&1)*(BM*BK);
    bool more = (t+1 < nt);

    // ---- P0: read a(ih0)+b(jh0); stage Ah0(t+1); MFMA quad (0,0); vmcnt(4)
    #pragma unroll
    for (int i=0;i<4;i++){ a[i][0] = lds_a(Ab,0,i,0); a[i][1] = lds_a(Ab,0,i,1); }
    #pragma unroll
    for (int j=0;j<2;j++){ b[0][j][0] = lds_b(Bb,0,j,0); b[0][j][1] = lds_b(Bb,0,j,1); }
    if (more) stage_half(t+1, 0);
    asm volatile("s_barrier" ::: "memory");
    asm volatile("s_waitcnt lgkmcnt(0)" ::: "memory");
    __builtin_amdgcn_s_setprio(1);
    #pragma unroll
    for (int i=0;i<4;i++)
      #pragma unroll
      for (int j=0;j<2;j++){
        acc[i][j] = __builtin_amdgcn_mfma_f32_16x16x32_bf16(a[i][0], b[0][j][0], acc[i][j], 0,0,0);
        acc[i][j] = __builtin_amdgcn_mfma_f32_16x16x32_bf16(a[i][1], b[0][j][1], acc[i][j], 0,0,0);
      }
    __builtin_amdgcn_s_setprio(0);
    if (more) asm volatile("s_waitcnt vmcnt(4)" ::: "memory");   // Bh1(t) resident for P1
    else      asm volatile("s_waitcnt vmcnt(2)" ::: "memory");
    asm volatile("s_barrier" ::: "memory");

    // ---- P1: read b(jh1); stage Bh0(t+1); MFMA quad (0,1); vmcnt(4)
    #pragma unroll
    for (int j=0;j<2;j++){ b[1][j][0] = lds_b(Bb,1,j,0); b[1][j][1] = lds_b(Bb,1,j,1); }
    if (more) stage_half(t+1, 1);
    asm volatile("s_barrier" ::: "memory");
    asm volatile("s_waitcnt lgkmcnt(0)" ::: "memory");
    __builtin_amdgcn_s_setprio(1);
    #pragma unroll
    for (int i=0;i<4;i++)
      #pragma unroll
      for (int j=0;j<2;j++){
        acc[i][2+j] = __builtin_amdgcn_mfma_f32_16x16x32_bf16(a[i][0], b[1][j][0], acc[i][2+j], 0,0,0);
        acc[i][2+j] = __builtin_amdgcn_mfma_f32_16x16x32_bf16(a[i][1], b[1][j][1], acc[i][2+j], 0,0,0);
      }
    __builtin_amdgcn_s_setprio(0);
    if (more) asm volatile("s_waitcnt vmcnt(4)" ::: "memory");   // Ah1(t) resident for P2
    else      asm volatile("s_waitcnt vmcnt(0)" ::: "memory");
    asm volatile("s_barrier" ::: "memory");

    // ---- P2: read a(ih1); stage Bh1(t+1); MFMA quad (1,1); no wait
    #pragma unroll
    for (int i=0;i<4;i++){ a[i][0] = lds_a(Ab,1,i,0); a[i][1] = lds_a(Ab,1,i,1); }
    if (more) stage_half(t+1, 2);
    asm volatile("s_barrier" ::: "memory");
    asm volatile("s_waitcnt lgkmcnt(0)" ::: "memory");
    __builtin_amdgcn_s_setprio(1);
    #pragma unroll
    for (int i=0;i<4;i++)
      #pragma unroll
      for (int j=0;j<2;j++){
        acc[4+i][2+j] = __builtin_amdgcn_mfma_f32_16x16x32_bf16(a[i][0], b[1][j][0], acc[4+i][2+j], 0,0,0);
        acc[4+i][2+j] = __builtin_amdgcn_mfma_f32_16x16x32_bf16(a[i][1], b[1][j][1], acc[4+i][2+j], 0,0,0);
      }
    __builtin_amdgcn_s_setprio(0);
    asm volatile("s_barrier" ::: "memory");

    // ---- P3: no reads; stage Ah1(t+1); MFMA quad (1,0); vmcnt(4)
    if (more) stage_half(t+1, 3);
    asm volatile("s_barrier" ::: "memory");
    __builtin_amdgcn_s_setprio(1);
    #pragma unroll
    for (int i=0;i<4;i++)
      #pragma unroll
      for (int j=0;j<2;j++){
        acc[4+i][j] = __builtin_amdgcn_mfma_f32_16x16x32_bf16(a[i][0], b[0][j][0], acc[4+i][j], 0,0,0);
        acc[4+i][j] = __builtin_amdgcn_mfma_f32_16x16x32_bf16(a[i][1], b[0][j][1], acc[4+i][j], 0,0,0);
      }
    __builtin_amdgcn_s_setprio(0);
    if (more) asm volatile("s_waitcnt vmcnt(4)" ::: "memory");   // Ah0,Bh0(t+1) resident for next P0
    asm volatile("s_barrier" ::: "memory");
  }

  // epilogue: C/D layout col=lane&15, row=(lane>>4)*4+reg  [verified m89/m91]
  // acc[ai][bj]: row = bm + (ai>>2)*128 + wm*64 + (ai&3)*16 + lr*4
  //              col = bn + (bj>>1)*128 + wn*32 + (bj&1)*16 + lc
  int lr = lane >> 4, lc = lane & 15;
  if (EPI == 3){
    #pragma unroll
    for (int ai=0;ai<8;ai++){
      #pragma unroll
      for (int bj=0;bj<4;bj++){
        int col  = bn + (bj>>1)*128 + wn*32 + (bj&1)*16 + lc;
        int row0 = bm + (ai>>2)*128 + wm*64 + (ai&3)*16 + lr*4;
        float bias_v = bias[col];
        #pragma unroll
        for (int rr=0; rr<4; rr++){
          size_t idx = (size_t)(row0+rr)*N + col;
          outf[idx] = acc[ai][bj][rr] + bias_v + residf[idx];
        }
      }
    }
  } else if (EPI == 2){
    // gate fold: sum_col gelu(v)*Wg2[col] -> gacc[row]
    #pragma unroll
    for (int ai=0;ai<8;ai++){
      float red[4] = {0.f,0.f,0.f,0.f};
      #pragma unroll
      for (int bj=0;bj<4;bj++){
        int col = bn + (bj>>1)*128 + wn*32 + (bj&1)*16 + lc;
        float bias_v = bias[col];
        float wv = Wv2[col];
        #pragma unroll
        for (int rr=0; rr<4; rr++){
          float v = acc[ai][bj][rr] + bias_v;
          red[rr] += geluf(v) * wv;
        }
      }
      int row0 = bm + (ai>>2)*128 + wm*64 + (ai&3)*16 + lr*4;
      #pragma unroll
      for (int rr=0; rr<4; rr++){
        float r = red[rr];
        r += __shfl_xor(r,1); r += __shfl_xor(r,2);
        r += __shfl_xor(r,4); r += __shfl_xor(r,8);
        if (lc == 0) atomicAdd(&gaccp[row0+rr], r);
      }
    }
  } else { // EPI == 4
    if (bn < 3072){
      #pragma unroll
      for (int ai=0;ai<8;ai++){
        #pragma unroll
        for (int bj=0;bj<4;bj++){
          int col  = bn + (bj>>1)*128 + wn*32 + (bj&1)*16 + lc;
          int row0 = bm + (ai>>2)*128 + wm*64 + (ai&3)*16 + lr*4;
          float bias_v = bias[col];
          #pragma unroll
          for (int rr=0; rr<4; rr++){
            int row = row0 + rr;
            float v = acc[ai][bj][rr] + bias_v;
            if (bn < 1024) {
              o_pv[(size_t)row*1024 + col] = f2bf(v);
            } else if (bn < 2048) {
              float kp = fast_tanh(v) * 3.14159265358979323846f;
              o_kp[(size_t)row*1024 + (col-1024)] = f2h(kp);
            } else {
              o_kv[(size_t)row*1024 + (col-2048)] = f2bf(v);
            }
          }
        }
      }
    } else {
      // bw fold: two dots with Wb2 columns -> bwacc[row*2+c]
      #pragma unroll
      for (int ai=0;ai<8;ai++){
        float r0[4] = {0.f,0.f,0.f,0.f};
        float r1[4] = {0.f,0.f,0.f,0.f};
        #pragma unroll
        for (int bj=0;bj<4;bj++){
          int col = bn + (bj>>1)*128 + wn*32 + (bj&1)*16 + lc;
          float bias_v = bias[col];
          int kb = col - 3072;
          float w0 = Wb2f[kb*2], w1 = Wb2f[kb*2+1];
          #pragma unroll
          for (int rr=0; rr<4; rr++){
            float v = acc[ai][bj][rr] + bias_v;
            float gl = geluf(v);
            r0[rr] += gl*w0;
            r1[rr] += gl*w1;
          }
        }
        int row0 = bm + (ai>>2)*128 + wm*64 + (ai&3)*16 + lr*4;
        #pragma unroll
        for (int rr=0; rr<4; rr++){
          float a2 = r0[rr], b2 = r1[rr];
          a2 += __shfl_xor(a2,1); a2 += __shfl_xor(a2,2); a2 += __shfl_xor(a2,4); a2 += __shfl_xor(a2,8);
          b2 += __shfl_xor(b2,1); b2 += __shfl_xor(b2,2); b2 += __shfl_xor(b2,4); b2 += __shfl_xor(b2,8);
          if (lc == 0){
            atomicAdd(&bwaccp[(size_t)(row0+rr)*2],   a2);
            atomicAdd(&bwaccp[(size_t)(row0+rr)*2+1], b2);
          }
        }
      }
    }
  }
}

// ---------------- gate sigmoid + cumsum over L: one 1024-thread block per batch ----------------
__global__ __launch_bounds__(1024) void k_gscan(const float* __restrict__ gacc,
                                                const float* __restrict__ bg2,
                                                float* __restrict__ g, float* __restrict__ gc){
  __shared__ float sa[1024];
  int b = blockIdx.x, tid = threadIdx.x;
  int base = b*L_ + tid*4;
  float bb = bg2[0];
  float v0 = 1.f/(1.f+__expf(-(gacc[base]   + bb)));
  float v1 = 1.f/(1.f+__expf(-(gacc[base+1] + bb)));
  float v2 = 1.f/(1.f+__expf(-(gacc[base+2] + bb)));
  float v3 = 1.f/(1.f+__expf(-(gacc[base+3] + bb)));
  float s0 = v0, s1 = s0+v1, s2 = s1+v2, s3 = s2+v3;
  sa[tid] = s3; __syncthreads();
  for (int o=1;o<1024;o<<=1){
    float t = sa[tid] + ((tid>=o) ? sa[tid-o] : 0.f);
    __syncthreads();
    sa[tid] = t;
    __syncthreads();
  }
  float ex = sa[tid] - s3;
  g[base]=v0; g[base+1]=v1; g[base+2]=v2; g[base+3]=v3;
  gc[base]=ex+s0; gc[base+1]=ex+s1; gc[base+2]=ex+s2; gc[base+3]=ex+s3;
}

// ---------------- finish blend weights: softmax2 over bwacc ----------------
__global__ void k_finishbw(const float* __restrict__ bwacc, const float* __restrict__ bb2,
                           float2* __restrict__ bw){
  int t = blockIdx.x*256 + threadIdx.x;
  float a = bwacc[(size_t)t*2]   + bb2[0];
  float b = bwacc[(size_t)t*2+1] + bb2[1];
  float m = fmaxf(a,b);
  float e0 = __expf(a-m), e1 = __expf(b-m);
  float inv = 1.0f/(e0+e1);
  bw[t] = make_float2(e0*inv, e1*inv);
}

// ---------------- scan pass 1: per-chunk partial sums (4 channels/thread) ----------------
__global__ void k_scan_partial(const bf16* __restrict__ PV, const bf16* __restrict__ KV,
                               const ushort* __restrict__ KP, const float* __restrict__ g,
                               const ushort* __restrict__ ppH, float* __restrict__ PS){
  int tid = threadIdx.x;
  int d0 = tid*4;
  int j = blockIdx.x, b = blockIdx.y;
  int l0 = j*LCH;
  float pkc[4]={0,0,0,0}, pks[4]={0,0,0,0};
  if (l0 > 0){
    size_t pidx = ((size_t)b*L_ + l0-1)*D_ + d0;
    ushort4 up = *(const ushort4*)(KP+pidx);
    float ph0=h2f(up.x), ph1=h2f(up.y), ph2=h2f(up.z), ph3=h2f(up.w);
    __sincosf(ph0,&pks[0],&pkc[0]); __sincosf(ph1,&pks[1],&pkc[1]);
    __sincosf(ph2,&pks[2],&pkc[2]); __sincosf(ph3,&pks[3],&pkc[3]);
  }
  float p0[4]={0,0,0,0}, p1[4]={0,0,0,0}, p2[4]={0,0,0,0}, p3[4]={0,0,0,0};
  for (int l=l0; l<l0+LCH; l++){
    size_t idx = ((size_t)b*L_ + l)*D_ + d0;
    ushort4 upv = *(const ushort4*)(PV+idx);
    ushort4 ukv = *(const ushort4*)(KV+idx);
    ushort4 ukp = *(const ushort4*)(KP+idx);
    ushort4 upp = *(const ushort4*)(ppH + (size_t)l*D_ + d0);
    float gl = g[b*L_ + l];
    float pvv[4]={us2f(upv.x),us2f(upv.y),us2f(upv.z),us2f(upv.w)};
    float kvv[4]={us2f(ukv.x),us2f(ukv.y),us2f(ukv.z),us2f(ukv.w)};
    float kpv[4]={h2f(ukp.x),h2f(ukp.y),h2f(ukp.z),h2f(ukp.w)};
    float phv[4]={h2f(upp.x),h2f(upp.y),h2f(upp.z),h2f(upp.w)};
    #pragma unroll
    for (int c=0;c<4;c++){
      float sn, cs; __sincosf(phv[c], &sn, &cs);
      float kc, ks; __sincosf(kpv[c], &ks, &kc);
      float kvg = kvv[c]*gl;
      p0[c] += cs*pvv[c]; p1[c] += sn*pvv[c];
      p2[c] += pkc[c]*kvg; p3[c] += pks[c]*kvg;
      pkc[c]=kc; pks[c]=ks;
    }
  }
  size_t base = ((size_t)b*CCH + j)*D_ + d0;
  size_t plane = (size_t)B_*CCH*D_;
  #pragma unroll
  for (int c=0;c<4;c++){
    PS[0*plane + base + c] = p0[c];
    PS[1*plane + base + c] = p1[c];
    PS[2*plane + base + c] = p2[c];
    PS[3*plane + base + c] = p3[c];
  }
}

// ---------------- exclusive prefix over chunks (in place), one thread per (q,b,d) ----------------
__global__ void k_prefix(float* __restrict__ PS){
  int idx = blockIdx.x*256 + threadIdx.x;   // over 4*B_*D_
  int q = idx >> 12;
  int rem = idx & 4095;
  int b = rem >> 10, d = rem & 1023;
  size_t plane = (size_t)B_*CCH*D_;
  float* base = PS + (size_t)q*plane + (size_t)b*CCH*D_ + d;
  float s = 0.0f;
  for (int j=0;j<CCH;j+=4){
    float v0 = base[(size_t)(j  )*D_];
    float v1 = base[(size_t)(j+1)*D_];
    float v2 = base[(size_t)(j+2)*D_];
    float v3 = base[(size_t)(j+3)*D_];
    base[(size_t)(j  )*D_] = s; s += v0;
    base[(size_t)(j+1)*D_] = s; s += v1;
    base[(size_t)(j+2)*D_] = s; s += v2;
    base[(size_t)(j+3)*D_] = s; s += v3;
  }
}

// ---------------- scan pass 2: apply with carry + fused LayerNorm, emit LNB ----------------
__global__ void k_scan_apply(const bf16* __restrict__ PV, const bf16* __restrict__ KV,
                             const ushort* __restrict__ KP, const float* __restrict__ g,
                             const ushort* __restrict__ ppH, const float* __restrict__ PS,
                             const float* __restrict__ gc, const float2* __restrict__ bw,
                             const float* __restrict__ ln_g, const float* __restrict__ ln_b,
                             bf16* __restrict__ LNB){
  __shared__ float sA[4], sB[4];
  int tid = threadIdx.x;
  int d0 = tid*4;
  int j = blockIdx.x, b = blockIdx.y;
  int l0 = j*LCH;
  size_t base = ((size_t)b*CCH + j)*D_ + d0;
  size_t plane = (size_t)B_*CCH*D_;
  float mc[4], ms[4], kcm[4], ksm[4];
  #pragma unroll
  for (int c=0;c<4;c++){
    mc[c]  = PS[0*plane+base+c]; ms[c]  = PS[1*plane+base+c];
    kcm[c] = PS[2*plane+base+c]; ksm[c] = PS[3*plane+base+c];
  }
  float pkc[4]={0,0,0,0}, pks[4]={0,0,0,0};
  if (l0 > 0){
    size_t pidx = ((size_t)b*L_ + l0-1)*D_ + d0;
    ushort4 up = *(const ushort4*)(KP+pidx);
    float ph0=h2f(up.x), ph1=h2f(up.y), ph2=h2f(up.z), ph3=h2f(up.w);
    __sincosf(ph0,&pks[0],&pkc[0]); __sincosf(ph1,&pks[1],&pkc[1]);
    __sincosf(ph2,&pks[2],&pkc[2]); __sincosf(ph3,&pks[3],&pkc[3]);
  }
  float4 gv = *(const float4*)&ln_g[d0];
  float4 bv = *(const float4*)&ln_b[d0];
  int wv = tid >> 6, ln = tid & 63;
  for (int l=l0; l<l0+LCH; l++){
    size_t idx = ((size_t)b*L_ + l)*D_ + d0;
    ushort4 upv = *(const ushort4*)(PV+idx);
    ushort4 ukv = *(const ushort4*)(KV+idx);
    ushort4 ukp = *(const ushort4*)(KP+idx);
    ushort4 upp = *(const ushort4*)(ppH + (size_t)l*D_ + d0);
    float gl = g[b*L_ + l];
    float gcv = fmaxf(gc[b*L_+l], 1.0f);
    float rs = 0.03125f * rsqrtf(gcv);
    float2 w = bw[b*L_+l];
    float pvv[4]={us2f(upv.x),us2f(upv.y),us2f(upv.z),us2f(upv.w)};
    float kvv[4]={us2f(ukv.x),us2f(ukv.y),us2f(ukv.z),us2f(ukv.w)};
    float kpv[4]={h2f(ukp.x),h2f(ukp.y),h2f(ukp.z),h2f(ukp.w)};
    float phv[4]={h2f(upp.x),h2f(upp.y),h2f(upp.z),h2f(upp.w)};
    float bl[4];
    #pragma unroll
    for (int c=0;c<4;c++){
      float sn, cs; __sincosf(phv[c], &sn, &cs);
      float kc, ks; __sincosf(kpv[c], &ks, &kc);
      mc[c] += cs*pvv[c]; ms[c] += sn*pvv[c];
      float pos_ret = (cs*mc[c] + sn*ms[c]) * 0.03125f;
      float kvg = kvv[c]*gl;
      kcm[c] += pkc[c]*kvg; ksm[c] += pks[c]*kvg;
      float kv_ret = (kc*kcm[c] + ks*ksm[c]) * rs;
      bl[c] = w.x*pos_ret + w.y*kv_ret;
      pkc[c]=kc; pks[c]=ks;
    }
    // fused LayerNorm over D (block covers full row)
    float s  = bl[0]+bl[1]+bl[2]+bl[3];
    float s2 = bl[0]*bl[0]+bl[1]*bl[1]+bl[2]*bl[2]+bl[3]*bl[3];
    #pragma unroll
    for (int o=1;o<64;o<<=1){ s += __shfl_xor(s,o); s2 += __shfl_xor(s2,o); }
    if (ln == 0){ sA[wv] = s; sB[wv] = s2; }
    __syncthreads();
    float ts  = sA[0]+sA[1]+sA[2]+sA[3];
    float ts2 = sB[0]+sB[1]+sB[2]+sB[3];
    __syncthreads();
    float mu   = ts * (1.0f/D_);
    float var  = ts2 * (1.0f/D_) - mu*mu;
    float rstd = rsqrtf(var + 1e-5f);
    ushort4 ou;
    ou.x = f2us((bl[0]-mu)*rstd*gv.x + bv.x);
    ou.y = f2us((bl[1]-mu)*rstd*gv.y + bv.y);
    ou.z = f2us((bl[2]-mu)*rstd*gv.z + bv.z);
    ou.w = f2us((bl[3]-mu)*rstd*gv.w + bv.w);
    *(ushort4*)((ushort*)LNB + idx) = ou;
  }
}

extern "C" void kernel_launch(void* const* d_in, const int* in_sizes, int n_in,
                              void* d_out, int out_size, void* d_ws, size_t ws_size,
                              hipStream_t stream) {
  const float* x     = (const float*)d_in[0];
  const float* phases= (const float*)d_in[1];
  const float* Wpv   = (const float*)d_in[2];
  const float* bpv   = (const float*)d_in[3];
  const float* Wk    = (const float*)d_in[4];
  const float* bk    = (const float*)d_in[5];
  const float* Wkv   = (const float*)d_in[6];
  const float* bkv   = (const float*)d_in[7];
  const float* Wg1   = (const float*)d_in[8];
  const float* bg1   = (const float*)d_in[9];
  const float* Wg2   = (const float*)d_in[10];
  const float* bg2   = (const float*)d_in[11];
  const float* Wb1   = (const float*)d_in[12];
  const float* bb1   = (const float*)d_in[13];
  const float* Wb2   = (const float*)d_in[14];
  const float* bb2   = (const float*)d_in[15];
  const float* ln_g  = (const float*)d_in[16];
  const float* ln_b  = (const float*)d_in[17];
  const float* Wo    = (const float*)d_in[18];
  const float* bo    = (const float*)d_in[19];
  float* out = (float*)d_out;

  char* ws = (char*)d_ws;
  size_t off = 0;
  auto alloc = [&](size_t bytes)->char*{
    char* p = ws + off; off += (bytes + 255) & ~(size_t)255; return p;
  };
  bf16*  xb   = (bf16*)alloc((size_t)M_*D_*2);
  bf16*  WfT  = (bf16*)alloc((size_t)NF*D_*2);     // [WpvT|WkT|WkvT|Wb1T], ld=1024
  bf16*  Wg1T = (bf16*)alloc((size_t)D_*2*D_*2);   // 1024 x 2048
  bf16*  WoT  = (bf16*)alloc((size_t)D_*D_*2);
  bf16*  PV   = (bf16*)alloc((size_t)M_*D_*2);
  bf16*  KV   = (bf16*)alloc((size_t)M_*D_*2);
  ushort* KP  = (ushort*)alloc((size_t)M_*D_*2);   // fp16 key phase
  ushort* ppH = (ushort*)alloc((size_t)L_*D_*2);   // fp16 pos phases
  bf16*  LNB  = (bf16*)alloc((size_t)M_*D_*2);
  float* gbuf  = (float*)alloc((size_t)M_*4);
  float* gcbuf = (float*)alloc((size_t)M_*4);
  float2* bwbuf= (float2*)alloc((size_t)M_*8);
  float* PS    = (float*)alloc((size_t)4*B_*CCH*D_*4);
  float* biasF = (float*)alloc((size_t)NF*4);
  // contiguous zero region: gacc | bwacc | zeros
  float* gacc  = (float*)alloc((size_t)M_*4);          // 65536 B
  float* bwacc = (float*)alloc((size_t)M_*2*4);        // 131072 B
  bf16*  zeros = (bf16*)alloc(256);
  int nzero = (M_ + 2*M_ + 64);

  k_zeroN<<<(nzero+255)/256,256,0,stream>>>(gacc, nzero);
  k_cvt<<<(M_*D_)/1024, 256, 0, stream>>>(x, xb);
  k_cvt_pp<<<(L_*D_)/1024, 256, 0, stream>>>(phases, ppH);

  dim3 tb(32,8);
  k_ctr<<<dim3(D_/32, D_/32), tb, 0, stream>>>(Wpv, WfT,                       D_, D_);
  k_ctr<<<dim3(D_/32, D_/32), tb, 0, stream>>>(Wk,  WfT + (size_t)1024*D_,     D_, D_);
  k_ctr<<<dim3(D_/32, D_/32), tb, 0, stream>>>(Wkv, WfT + (size_t)2048*D_,     D_, D_);
  k_ctr<<<dim3((D_/2)/32, D_/32), tb, 0, stream>>>(Wb1, WfT + (size_t)3072*D_, D_, D_/2);
  k_ctr<<<dim3(D_/32, 2*D_/32), tb, 0, stream>>>(Wg1, Wg1T, 2*D_, D_);
  k_ctr<<<dim3(D_/32, D_/32), tb, 0, stream>>>(Wo,  WoT,  D_, D_);
  k_pack_bias<<<NF/256,256,0,stream>>>(bpv, bk, bkv, bb1, biasF);

  // fused PV/KP/KV + bw-fold : x @ [Wpv|Wk|Wkv|Wb1]  (M x 3584 x 1024)
  k_gemm<4,false><<<dim3(NF/BN, M_/BM),512,0,stream>>>(
      xb, D_, WfT, D_, biasF, zeros, PV, KP, KV, nullptr, Wb2, nullptr, bwacc,
      nullptr, nullptr, NF, D_);
  // concat GEMM with gate-fold: gacc[row] += sum gelu(...)*Wg2  (M x 1024 x 2048)
  k_gemm<2,true><<<dim3(D_/BN, M_/BM),512,0,stream>>>(
      xb, D_, Wg1T, 2*D_, bg1, zeros, nullptr, nullptr, nullptr, Wg2, nullptr, gacc, nullptr,
      nullptr, nullptr, D_, 2*D_);
  // gate sigmoid + cumsum
  k_gscan<<<B_,1024,0,stream>>>(gacc, bg2, gbuf, gcbuf);
  // blend weights softmax
  k_finishbw<<<M_/256,256,0,stream>>>(bwacc, bb2, bwbuf);
  // chunked scans -> LN'd blended
  dim3 sg(CCH, B_);
  k_scan_partial<<<sg,256,0,stream>>>(PV, KV, KP, gbuf, ppH, PS);
  k_prefix<<<(4*B_*D_)/256,256,0,stream>>>(PS);
  k_scan_apply<<<sg,256,0,stream>>>(PV, KV, KP, gbuf, ppH, PS, gcbuf, bwbuf, ln_g, ln_b, LNB);
  // out = x + LN@Wo + bo   (fp32 out, fp32 resid)
  k_gemm<3,false><<<dim3(D_/BN, M_/BM),512,0,stream>>>(
      LNB, D_, WoT, D_, bo, zeros, nullptr, nullptr, nullptr, nullptr, nullptr, nullptr, nullptr,
      out, x, D_, D_);
}

// Round 7
// 597.179 us; speedup vs baseline: 1.0066x; 1.0066x over previous
//
#include <hip/hip_runtime.h>
#include <hip/hip_bf16.h>
#include <math.h>

using bf16 = __hip_bfloat16;
typedef __bf16 v8bf __attribute__((ext_vector_type(8)));
typedef float v4f __attribute__((ext_vector_type(4)));

#define B_ 4
#define L_ 4096
#define D_ 1024
#define M_ (B_*L_)
#define CCH 128
#define LCH (L_/CCH)
#define NF 3584   // fused N: Wpv(1024) | Wk(1024) | Wkv(1024) | Wb1(512)

__device__ __forceinline__ float bf2f(bf16 v){ return __bfloat162float(v); }
__device__ __forceinline__ bf16 f2bf(float v){ return __float2bfloat16(v); }
__device__ __forceinline__ float us2f(ushort u){ union{unsigned u32; float f;}c; c.u32=((unsigned)u)<<16; return c.f; }
__device__ __forceinline__ ushort f2us(float v){ bf16 h=__float2bfloat16(v); return *(ushort*)&h; }
__device__ __forceinline__ float h2f(ushort u){ union{ushort s; _Float16 h;}c; c.s=u; return (float)c.h; }
__device__ __forceinline__ ushort f2h(float v){ union{ushort s; _Float16 h;}c; c.h=(_Float16)v; return c.s; }

// async global->LDS, 16B per lane, dest = wave-uniform base + lane*16  [m97 pattern]
__device__ __forceinline__ void g2l16(const void* g, void* l){
  __builtin_amdgcn_global_load_lds(
    (const __attribute__((address_space(1))) unsigned int*)g,
    (__attribute__((address_space(3))) unsigned int*)l, 16, 0, 0);
}

// ---------------- zero a float region (ws is poisoned 0xAA each launch) ----------------
__global__ void k_zeroN(float* __restrict__ p, int n){
  int i = blockIdx.x*256 + threadIdx.x;
  if (i < n) p[i] = 0.0f;
}

// ---------------- x fp32 -> bf16 ----------------
__global__ void k_cvt(const float* __restrict__ in, bf16* __restrict__ out){
  int i = (blockIdx.x*256 + threadIdx.x)*4;
  float4 v = *(const float4*)(in + i);
  out[i]   = f2bf(v.x);
  out[i+1] = f2bf(v.y);
  out[i+2] = f2bf(v.z);
  out[i+3] = f2bf(v.w);
}

// ---------------- pos_phases fp32 -> fp16 ----------------
__global__ void k_cvt_pp(const float* __restrict__ in, ushort* __restrict__ out){
  int i = (blockIdx.x*256 + threadIdx.x)*4;
  float4 v = *(const float4*)(in + i);
  out[i]   = f2h(v.x);
  out[i+1] = f2h(v.y);
  out[i+2] = f2h(v.z);
  out[i+3] = f2h(v.w);
}

// ---------------- weight convert+transpose fp32 (R x C) -> bf16 (C x R) ----------------
__global__ void k_ctr(const float* __restrict__ in, bf16* __restrict__ out, int R, int C){
  __shared__ float tile[32][33];
  int c0 = blockIdx.x*32, r0 = blockIdx.y*32;
  #pragma unroll
  for (int i=0;i<32;i+=8)
    tile[threadIdx.y+i][threadIdx.x] = in[(size_t)(r0+threadIdx.y+i)*C + c0+threadIdx.x];
  __syncthreads();
  #pragma unroll
  for (int i=0;i<32;i+=8)
    out[(size_t)(c0+threadIdx.y+i)*R + r0+threadIdx.x] = f2bf(tile[threadIdx.x][threadIdx.y+i]);
}

// ---------------- pack fused bias [bpv|bk|bkv|bb1] ----------------
__global__ void k_pack_bias(const float* __restrict__ bpv, const float* __restrict__ bk,
                            const float* __restrict__ bkv, const float* __restrict__ bb1,
                            float* __restrict__ bf){
  int i = blockIdx.x*256 + threadIdx.x;
  float v;
  if (i < 1024) v = bpv[i];
  else if (i < 2048) v = bk[i-1024];
  else if (i < 3072) v = bkv[i-2048];
  else v = bb1[i-3072];
  bf[i] = v;
}

__device__ __forceinline__ float geluf(float v){
  return 0.5f*v*(1.0f + erff(v*0.70710678118654752f));
}
__device__ __forceinline__ float fast_tanh(float v){
  float a = fabsf(v);
  float e = __expf(-2.0f*a);
  float t = (1.0f - e)/(1.0f + e);
  return copysignf(t, v);
}

// ---------------- MFMA GEMM: 256x256 tile, BK=64, 8 waves, minimal-sync free-run ----------------
// R4 post-mortem: 8 barriers + 4 lgkm(0) + 3 vmcnt per K-tile kept 8 waves in
// lockstep -> LDS drain and MFMA serialized phase-by-phase (~7300 cyc/K-tile vs
// ~2500 pipe floor). Correctness needs only ONE sync point per K-tile:
//   body t: stage ALL of tile t+1 at top (8 g2l16, buf^1) -> 4 read+MFMA
//   quadrants, NO barriers/waits (compiler inserts counted lgkmcnt; waves skew
//   and overlap LDS with MFMA) -> __syncthreads() (= vmcnt(0)+lgkmcnt(0)+barrier:
//   WAR, my reads of buf(t) sampled; RAW, my 8 stages of t+1 landed -- issued a
//   full body ~3000cyc earlier, so the drain is cheap).
// R6 note: raw asm lgkm/vmcnt/s_barrier triplet replaced by __syncthreads()
// (identical emitted semantics per guide, but via the compiler's own
// convergence-aware path) after two container failures -- defensive only.
// T1 chunked XCD swizzle (kept: FETCH -23%), T2 LDS XOR swizzle (kept: 0
// conflicts), T5 setprio around MFMA clusters (kept).
#define BM 256
#define BN 256
#define BK 64

template<int EPI, bool CONCAT>
__global__ __launch_bounds__(512) void k_gemm(
    const bf16* __restrict__ A, int lda,
    const bf16* __restrict__ Bt, int ldb,
    const float* __restrict__ bias,
    const bf16* __restrict__ zeros,
    bf16* __restrict__ o_pv, ushort* __restrict__ o_kp, bf16* __restrict__ o_kv,
    const float* __restrict__ Wv2, const float* __restrict__ Wb2f,
    float* __restrict__ gaccp, float* __restrict__ bwaccp,
    float* __restrict__ outf, const float* __restrict__ residf,
    int N, int Ktot)
{
  __shared__ __align__(16) ushort As[2*BM*BK];
  __shared__ __align__(16) ushort Bs[2*BN*BK];
  int tid = threadIdx.x;
  int lane = tid & 63, wave = tid >> 6;      // 8 waves
  int wm = wave >> 2, wn = wave & 3;         // 2 (M) x 4 (N) wave grid
  // T1: chunked XCD-aware block swizzle (nwg % 8 == 0 for all launches)
  int nwgx = gridDim.x;
  int flat = blockIdx.y * nwgx + blockIdx.x;
  int chunk = (nwgx * gridDim.y) >> 3;
  int newid = (flat & 7) * chunk + (flat >> 3);
  int bn = (newid % nwgx) * BN, bm = (newid / nwgx) * BM;

  v4f zero = {0.f,0.f,0.f,0.f};
  v4f acc[8][4];
  #pragma unroll
  for (int i=0;i<8;i++)
    #pragma unroll
    for (int j=0;j<4;j++) acc[i][j] = zero;

  int mr = lane & 15, g4 = lane >> 4;        // MFMA fragment addressing
  int srow = lane >> 3, sseg = lane & 7;     // staging: 8 rows x 8 k-segments per wave
  int swzs = (sseg ^ srow) * 8;              // pre-swizzled source col (elements)

  // stage one half-tile of K-tile t into buffer t&1.
  // which: 0=A rows 0-127, 1=B rows 0-127, 2=B rows 128-255, 3=A rows 128-255
  auto stage_half = [&](int t, int which){
    int buf = t & 1;
    int kk = t * BK;
    bool isA = (which==0) || (which==3);
    int rbase = (which==0 || which==1) ? 0 : 128;
    ushort* dst = (isA ? As : Bs) + buf*(BM*BK);
    #pragma unroll
    for (int p=0;p<2;p++){
      int r = rbase + p*64 + wave*8 + srow;
      const bf16* src;
      if (isA){
        if (!CONCAT || kk < D_) {
          src = A + (size_t)(bm + r)*lda + (size_t)kk + swzs;
        } else {
          int m = bm + r;
          int l = m & (L_-1);
          src = (l==0) ? (zeros + swzs)
                       : (A + (size_t)(m-1)*lda + (size_t)(kk - D_) + swzs);
        }
      } else {
        src = Bt + (size_t)(bn + r)*ldb + (size_t)kk + swzs;
      }
      g2l16(src, dst + (size_t)(rbase + p*64 + wave*8)*BK);
    }
  };

  // swizzled LDS fragment reads
  auto lds_a = [&](const ushort* Ab, int ih, int i, int ks)->v8bf{
    int row = ih*128 + wm*64 + i*16 + mr;
    int off = row*128 + ((ks*64 + g4*16) ^ ((mr&7)<<4));
    return *(const v8bf*)((const char*)Ab + off);
  };
  auto lds_b = [&](const ushort* Bb, int jh, int j, int ks)->v8bf{
    int row = jh*128 + wn*32 + j*16 + mr;
    int off = row*128 + ((ks*64 + g4*16) ^ ((mr&7)<<4));
    return *(const v8bf*)((const char*)Bb + off);
  };

  int nt = Ktot / BK;
  // prologue: stage tile 0 fully; full drain + barrier
  stage_half(0,0); stage_half(0,1); stage_half(0,2); stage_half(0,3);
  __syncthreads();

  v8bf a[4][2];       // current ih's A fragments [i][ks]
  v8bf b[2][2][2];    // both B halves [jh][j][ks]

  for (int t=0; t<nt; ++t){
    const ushort* Ab = As + (t&1)*(BM*BK);
    const ushort* Bb = Bs + (t&1)*(BM*BK);
    bool more = (t+1 < nt);

    // stage ALL of tile t+1 up front (other buffer) -> max issue-to-wait distance
    if (more){
      stage_half(t+1, 0); stage_half(t+1, 1);
      stage_half(t+1, 2); stage_half(t+1, 3);
    }

    // ---- Q0: (ih0, jh0) ----
    #pragma unroll
    for (int i=0;i<4;i++){ a[i][0] = lds_a(Ab,0,i,0); a[i][1] = lds_a(Ab,0,i,1); }
    #pragma unroll
    for (int j=0;j<2;j++){ b[0][j][0] = lds_b(Bb,0,j,0); b[0][j][1] = lds_b(Bb,0,j,1); }
    __builtin_amdgcn_s_setprio(1);
    #pragma unroll
    for (int i=0;i<4;i++)
      #pragma unroll
      for (int j=0;j<2;j++){
        acc[i][j] = __builtin_amdgcn_mfma_f32_16x16x32_bf16(a[i][0], b[0][j][0], acc[i][j], 0,0,0);
        acc[i][j] = __builtin_amdgcn_mfma_f32_16x16x32_bf16(a[i][1], b[0][j][1], acc[i][j], 0,0,0);
      }
    __builtin_amdgcn_s_setprio(0);

    // ---- Q1: (ih0, jh1) ----
    #pragma unroll
    for (int j=0;j<2;j++){ b[1][j][0] = lds_b(Bb,1,j,0); b[1][j][1] = lds_b(Bb,1,j,1); }
    __builtin_amdgcn_s_setprio(1);
    #pragma unroll
    for (int i=0;i<4;i++)
      #pragma unroll
      for (int j=0;j<2;j++){
        acc[i][2+j] = __builtin_amdgcn_mfma_f32_16x16x32_bf16(a[i][0], b[1][j][0], acc[i][2+j], 0,0,0);
        acc[i][2+j] = __builtin_amdgcn_mfma_f32_16x16x32_bf16(a[i][1], b[1][j][1], acc[i][2+j], 0,0,0);
      }
    __builtin_amdgcn_s_setprio(0);

    // ---- Q2: (ih1, jh1) ----
    #pragma unroll
    for (int i=0;i<4;i++){ a[i][0] = lds_a(Ab,1,i,0); a[i][1] = lds_a(Ab,1,i,1); }
    __builtin_amdgcn_s_setprio(1);
    #pragma unroll
    for (int i=0;i<4;i++)
      #pragma unroll
      for (int j=0;j<2;j++){
        acc[4+i][2+j] = __builtin_amdgcn_mfma_f32_16x16x32_bf16(a[i][0], b[1][j][0], acc[4+i][2+j], 0,0,0);
        acc[4+i][2+j] = __builtin_amdgcn_mfma_f32_16x16x32_bf16(a[i][1], b[1][j][1], acc[4+i][2+j], 0,0,0);
      }
    __builtin_amdgcn_s_setprio(0);

    // ---- Q3: (ih1, jh0) ----
    __builtin_amdgcn_s_setprio(1);
    #pragma unroll
    for (int i=0;i<4;i++)
      #pragma unroll
      for (int j=0;j<2;j++){
        acc[4+i][j] = __builtin_amdgcn_mfma_f32_16x16x32_bf16(a[i][0], b[0][j][0], acc[4+i][j], 0,0,0);
        acc[4+i][j] = __builtin_amdgcn_mfma_f32_16x16x32_bf16(a[i][1], b[0][j][1], acc[4+i][j], 0,0,0);
      }
    __builtin_amdgcn_s_setprio(0);

    // ---- single sync point per K-tile ----
    // __syncthreads = s_waitcnt vmcnt(0) lgkmcnt(0) + s_barrier:
    //   WAR: my ds_reads of buf(t) sampled before anyone re-stages this parity.
    //   RAW: my 8 stages of tile t+1 landed (issued a full body earlier -> cheap).
    __syncthreads();
  }

  // epilogue: C/D layout col=lane&15, row=(lane>>4)*4+reg  [verified m89/m91]
  // acc[ai][bj]: row = bm + (ai>>2)*128 + wm*64 + (ai&3)*16 + lr*4
  //              col = bn + (bj>>1)*128 + wn*32 + (bj&1)*16 + lc
  int lr = lane >> 4, lc = lane & 15;
  if (EPI == 3){
    #pragma unroll
    for (int ai=0;ai<8;ai++){
      #pragma unroll
      for (int bj=0;bj<4;bj++){
        int col  = bn + (bj>>1)*128 + wn*32 + (bj&1)*16 + lc;
        int row0 = bm + (ai>>2)*128 + wm*64 + (ai&3)*16 + lr*4;
        float bias_v = bias[col];
        #pragma unroll
        for (int rr=0; rr<4; rr++){
          size_t idx = (size_t)(row0+rr)*N + col;
          outf[idx] = acc[ai][bj][rr] + bias_v + residf[idx];
        }
      }
    }
  } else if (EPI == 2){
    // gate fold: sum_col gelu(v)*Wg2[col] -> gacc[row]
    #pragma unroll
    for (int ai=0;ai<8;ai++){
      float red[4] = {0.f,0.f,0.f,0.f};
      #pragma unroll
      for (int bj=0;bj<4;bj++){
        int col = bn + (bj>>1)*128 + wn*32 + (bj&1)*16 + lc;
        float bias_v = bias[col];
        float wv = Wv2[col];
        #pragma unroll
        for (int rr=0; rr<4; rr++){
          float v = acc[ai][bj][rr] + bias_v;
          red[rr] += geluf(v) * wv;
        }
      }
      int row0 = bm + (ai>>2)*128 + wm*64 + (ai&3)*16 + lr*4;
      #pragma unroll
      for (int rr=0; rr<4; rr++){
        float r = red[rr];
        r += __shfl_xor(r,1); r += __shfl_xor(r,2);
        r += __shfl_xor(r,4); r += __shfl_xor(r,8);
        if (lc == 0) atomicAdd(&gaccp[row0+rr], r);
      }
    }
  } else { // EPI == 4
    if (bn < 3072){
      #pragma unroll
      for (int ai=0;ai<8;ai++){
        #pragma unroll
        for (int bj=0;bj<4;bj++){
          int col  = bn + (bj>>1)*128 + wn*32 + (bj&1)*16 + lc;
          int row0 = bm + (ai>>2)*128 + wm*64 + (ai&3)*16 + lr*4;
          float bias_v = bias[col];
          #pragma unroll
          for (int rr=0; rr<4; rr++){
            int row = row0 + rr;
            float v = acc[ai][bj][rr] + bias_v;
            if (bn < 1024) {
              o_pv[(size_t)row*1024 + col] = f2bf(v);
            } else if (bn < 2048) {
              float kp = fast_tanh(v) * 3.14159265358979323846f;
              o_kp[(size_t)row*1024 + (col-1024)] = f2h(kp);
            } else {
              o_kv[(size_t)row*1024 + (col-2048)] = f2bf(v);
            }
          }
        }
      }
    } else {
      // bw fold: two dots with Wb2 columns -> bwacc[row*2+c]
      #pragma unroll
      for (int ai=0;ai<8;ai++){
        float r0[4] = {0.f,0.f,0.f,0.f};
        float r1[4] = {0.f,0.f,0.f,0.f};
        #pragma unroll
        for (int bj=0;bj<4;bj++){
          int col = bn + (bj>>1)*128 + wn*32 + (bj&1)*16 + lc;
          float bias_v = bias[col];
          int kb = col - 3072;
          float w0 = Wb2f[kb*2], w1 = Wb2f[kb*2+1];
          #pragma unroll
          for (int rr=0; rr<4; rr++){
            float v = acc[ai][bj][rr] + bias_v;
            float gl = geluf(v);
            r0[rr] += gl*w0;
            r1[rr] += gl*w1;
          }
        }
        int row0 = bm + (ai>>2)*128 + wm*64 + (ai&3)*16 + lr*4;
        #pragma unroll
        for (int rr=0; rr<4; rr++){
          float a2 = r0[rr], b2 = r1[rr];
          a2 += __shfl_xor(a2,1); a2 += __shfl_xor(a2,2); a2 += __shfl_xor(a2,4); a2 += __shfl_xor(a2,8);
          b2 += __shfl_xor(b2,1); b2 += __shfl_xor(b2,2); b2 += __shfl_xor(b2,4); b2 += __shfl_xor(b2,8);
          if (lc == 0){
            atomicAdd(&bwaccp[(size_t)(row0+rr)*2],   a2);
            atomicAdd(&bwaccp[(size_t)(row0+rr)*2+1], b2);
          }
        }
      }
    }
  }
}

// ---------------- gate sigmoid + cumsum over L: one 1024-thread block per batch ----------------
__global__ __launch_bounds__(1024) void k_gscan(const float* __restrict__ gacc,
                                                const float* __restrict__ bg2,
                                                float* __restrict__ g, float* __restrict__ gc){
  __shared__ float sa[1024];
  int b = blockIdx.x, tid = threadIdx.x;
  int base = b*L_ + tid*4;
  float bb = bg2[0];
  float v0 = 1.f/(1.f+__expf(-(gacc[base]   + bb)));
  float v1 = 1.f/(1.f+__expf(-(gacc[base+1] + bb)));
  float v2 = 1.f/(1.f+__expf(-(gacc[base+2] + bb)));
  float v3 = 1.f/(1.f+__expf(-(gacc[base+3] + bb)));
  float s0 = v0, s1 = s0+v1, s2 = s1+v2, s3 = s2+v3;
  sa[tid] = s3; __syncthreads();
  for (int o=1;o<1024;o<<=1){
    float t = sa[tid] + ((tid>=o) ? sa[tid-o] : 0.f);
    __syncthreads();
    sa[tid] = t;
    __syncthreads();
  }
  float ex = sa[tid] - s3;
  g[base]=v0; g[base+1]=v1; g[base+2]=v2; g[base+3]=v3;
  gc[base]=ex+s0; gc[base+1]=ex+s1; gc[base+2]=ex+s2; gc[base+3]=ex+s3;
}

// ---------------- finish blend weights: softmax2 over bwacc ----------------
__global__ void k_finishbw(const float* __restrict__ bwacc, const float* __restrict__ bb2,
                           float2* __restrict__ bw){
  int t = blockIdx.x*256 + threadIdx.x;
  float a = bwacc[(size_t)t*2]   + bb2[0];
  float b = bwacc[(size_t)t*2+1] + bb2[1];
  float m = fmaxf(a,b);
  float e0 = __expf(a-m), e1 = __expf(b-m);
  float inv = 1.0f/(e0+e1);
  bw[t] = make_float2(e0*inv, e1*inv);
}

// ---------------- scan pass 1: per-chunk partial sums (4 channels/thread) ----------------
__global__ void k_scan_partial(const bf16* __restrict__ PV, const bf16* __restrict__ KV,
                               const ushort* __restrict__ KP, const float* __restrict__ g,
                               const ushort* __restrict__ ppH, float* __restrict__ PS){
  int tid = threadIdx.x;
  int d0 = tid*4;
  int j = blockIdx.x, b = blockIdx.y;
  int l0 = j*LCH;
  float pkc[4]={0,0,0,0}, pks[4]={0,0,0,0};
  if (l0 > 0){
    size_t pidx = ((size_t)b*L_ + l0-1)*D_ + d0;
    ushort4 up = *(const ushort4*)(KP+pidx);
    float ph0=h2f(up.x), ph1=h2f(up.y), ph2=h2f(up.z), ph3=h2f(up.w);
    __sincosf(ph0,&pks[0],&pkc[0]); __sincosf(ph1,&pks[1],&pkc[1]);
    __sincosf(ph2,&pks[2],&pkc[2]); __sincosf(ph3,&pks[3],&pkc[3]);
  }
  float p0[4]={0,0,0,0}, p1[4]={0,0,0,0}, p2[4]={0,0,0,0}, p3[4]={0,0,0,0};
  for (int l=l0; l<l0+LCH; l++){
    size_t idx = ((size_t)b*L_ + l)*D_ + d0;
    ushort4 upv = *(const ushort4*)(PV+idx);
    ushort4 ukv = *(const ushort4*)(KV+idx);
    ushort4 ukp = *(const ushort4*)(KP+idx);
    ushort4 upp = *(const ushort4*)(ppH + (size_t)l*D_ + d0);
    float gl = g[b*L_ + l];
    float pvv[4]={us2f(upv.x),us2f(upv.y),us2f(upv.z),us2f(upv.w)};
    float kvv[4]={us2f(ukv.x),us2f(ukv.y),us2f(ukv.z),us2f(ukv.w)};
    float kpv[4]={h2f(ukp.x),h2f(ukp.y),h2f(ukp.z),h2f(ukp.w)};
    float phv[4]={h2f(upp.x),h2f(upp.y),h2f(upp.z),h2f(upp.w)};
    #pragma unroll
    for (int c=0;c<4;c++){
      float sn, cs; __sincosf(phv[c], &sn, &cs);
      float kc, ks; __sincosf(kpv[c], &ks, &kc);
      float kvg = kvv[c]*gl;
      p0[c] += cs*pvv[c]; p1[c] += sn*pvv[c];
      p2[c] += pkc[c]*kvg; p3[c] += pks[c]*kvg;
      pkc[c]=kc; pks[c]=ks;
    }
  }
  size_t base = ((size_t)b*CCH + j)*D_ + d0;
  size_t plane = (size_t)B_*CCH*D_;
  #pragma unroll
  for (int c=0;c<4;c++){
    PS[0*plane + base + c] = p0[c];
    PS[1*plane + base + c] = p1[c];
    PS[2*plane + base + c] = p2[c];
    PS[3*plane + base + c] = p3[c];
  }
}

// ---------------- exclusive prefix over chunks (in place), one thread per (q,b,d) ----------------
__global__ void k_prefix(float* __restrict__ PS){
  int idx = blockIdx.x*256 + threadIdx.x;   // over 4*B_*D_
  int q = idx >> 12;
  int rem = idx & 4095;
  int b = rem >> 10, d = rem & 1023;
  size_t plane = (size_t)B_*CCH*D_;
  float* base = PS + (size_t)q*plane + (size_t)b*CCH*D_ + d;
  float s = 0.0f;
  for (int j=0;j<CCH;j+=4){
    float v0 = base[(size_t)(j  )*D_];
    float v1 = base[(size_t)(j+1)*D_];
    float v2 = base[(size_t)(j+2)*D_];
    float v3 = base[(size_t)(j+3)*D_];
    base[(size_t)(j  )*D_] = s; s += v0;
    base[(size_t)(j+1)*D_] = s; s += v1;
    base[(size_t)(j+2)*D_] = s; s += v2;
    base[(size_t)(j+3)*D_] = s; s += v3;
  }
}

// ---------------- scan pass 2: apply with carry + fused LayerNorm, emit LNB ----------------
__global__ void k_scan_apply(const bf16* __restrict__ PV, const bf16* __restrict__ KV,
                             const ushort* __restrict__ KP, const float* __restrict__ g,
                             const ushort* __restrict__ ppH, const float* __restrict__ PS,
                             const float* __restrict__ gc, const float2* __restrict__ bw,
                             const float* __restrict__ ln_g, const float* __restrict__ ln_b,
                             bf16* __restrict__ LNB){
  __shared__ float sA[4], sB[4];
  int tid = threadIdx.x;
  int d0 = tid*4;
  int j = blockIdx.x, b = blockIdx.y;
  int l0 = j*LCH;
  size_t base = ((size_t)b*CCH + j)*D_ + d0;
  size_t plane = (size_t)B_*CCH*D_;
  float mc[4], ms[4], kcm[4], ksm[4];
  #pragma unroll
  for (int c=0;c<4;c++){
    mc[c]  = PS[0*plane+base+c]; ms[c]  = PS[1*plane+base+c];
    kcm[c] = PS[2*plane+base+c]; ksm[c] = PS[3*plane+base+c];
  }
  float pkc[4]={0,0,0,0}, pks[4]={0,0,0,0};
  if (l0 > 0){
    size_t pidx = ((size_t)b*L_ + l0-1)*D_ + d0;
    ushort4 up = *(const ushort4*)(KP+pidx);
    float ph0=h2f(up.x), ph1=h2f(up.y), ph2=h2f(up.z), ph3=h2f(up.w);
    __sincosf(ph0,&pks[0],&pkc[0]); __sincosf(ph1,&pks[1],&pkc[1]);
    __sincosf(ph2,&pks[2],&pkc[2]); __sincosf(ph3,&pks[3],&pkc[3]);
  }
  float4 gv = *(const float4*)&ln_g[d0];
  float4 bv = *(const float4*)&ln_b[d0];
  int wv = tid >> 6, ln = tid & 63;
  for (int l=l0; l<l0+LCH; l++){
    size_t idx = ((size_t)b*L_ + l)*D_ + d0;
    ushort4 upv = *(const ushort4*)(PV+idx);
    ushort4 ukv = *(const ushort4*)(KV+idx);
    ushort4 ukp = *(const ushort4*)(KP+idx);
    ushort4 upp = *(const ushort4*)(ppH + (size_t)l*D_ + d0);
    float gl = g[b*L_ + l];
    float gcv = fmaxf(gc[b*L_+l], 1.0f);
    float rs = 0.03125f * rsqrtf(gcv);
    float2 w = bw[b*L_+l];
    float pvv[4]={us2f(upv.x),us2f(upv.y),us2f(upv.z),us2f(upv.w)};
    float kvv[4]={us2f(ukv.x),us2f(ukv.y),us2f(ukv.z),us2f(ukv.w)};
    float kpv[4]={h2f(ukp.x),h2f(ukp.y),h2f(ukp.z),h2f(ukp.w)};
    float phv[4]={h2f(upp.x),h2f(upp.y),h2f(upp.z),h2f(upp.w)};
    float bl[4];
    #pragma unroll
    for (int c=0;c<4;c++){
      float sn, cs; __sincosf(phv[c], &sn, &cs);
      float kc, ks; __sincosf(kpv[c], &ks, &kc);
      mc[c] += cs*pvv[c]; ms[c] += sn*pvv[c];
      float pos_ret = (cs*mc[c] + sn*ms[c]) * 0.03125f;
      float kvg = kvv[c]*gl;
      kcm[c] += pkc[c]*kvg; ksm[c] += pks[c]*kvg;
      float kv_ret = (kc*kcm[c] + ks*ksm[c]) * rs;
      bl[c] = w.x*pos_ret + w.y*kv_ret;
      pkc[c]=kc; pks[c]=ks;
    }
    // fused LayerNorm over D (block covers full row)
    float s  = bl[0]+bl[1]+bl[2]+bl[3];
    float s2 = bl[0]*bl[0]+bl[1]*bl[1]+bl[2]*bl[2]+bl[3]*bl[3];
    #pragma unroll
    for (int o=1;o<64;o<<=1){ s += __shfl_xor(s,o); s2 += __shfl_xor(s2,o); }
    if (ln == 0){ sA[wv] = s; sB[wv] = s2; }
    __syncthreads();
    float ts  = sA[0]+sA[1]+sA[2]+sA[3];
    float ts2 = sB[0]+sB[1]+sB[2]+sB[3];
    __syncthreads();
    float mu   = ts * (1.0f/D_);
    float var  = ts2 * (1.0f/D_) - mu*mu;
    float rstd = rsqrtf(var + 1e-5f);
    ushort4 ou;
    ou.x = f2us((bl[0]-mu)*rstd*gv.x + bv.x);
    ou.y = f2us((bl[1]-mu)*rstd*gv.y + bv.y);
    ou.z = f2us((bl[2]-mu)*rstd*gv.z + bv.z);
    ou.w = f2us((bl[3]-mu)*rstd*gv.w + bv.w);
    *(ushort4*)((ushort*)LNB + idx) = ou;
  }
}

extern "C" void kernel_launch(void* const* d_in, const int* in_sizes, int n_in,
                              void* d_out, int out_size, void* d_ws, size_t ws_size,
                              hipStream_t stream) {
  const float* x     = (const float*)d_in[0];
  const float* phases= (const float*)d_in[1];
  const float* Wpv   = (const float*)d_in[2];
  const float* bpv   = (const float*)d_in[3];
  const float* Wk    = (const float*)d_in[4];
  const float* bk    = (const float*)d_in[5];
  const float* Wkv   = (const float*)d_in[6];
  const float* bkv   = (const float*)d_in[7];
  const float* Wg1   = (const float*)d_in[8];
  const float* bg1   = (const float*)d_in[9];
  const float* Wg2   = (const float*)d_in[10];
  const float* bg2   = (const float*)d_in[11];
  const float* Wb1   = (const float*)d_in[12];
  const float* bb1   = (const float*)d_in[13];
  const float* Wb2   = (const float*)d_in[14];
  const float* bb2   = (const float*)d_in[15];
  const float* ln_g  = (const float*)d_in[16];
  const float* ln_b  = (const float*)d_in[17];
  const float* Wo    = (const float*)d_in[18];
  const float* bo    = (const float*)d_in[19];
  float* out = (float*)d_out;

  char* ws = (char*)d_ws;
  size_t off = 0;
  auto alloc = [&](size_t bytes)->char*{
    char* p = ws + off; off += (bytes + 255) & ~(size_t)255; return p;
  };
  bf16*  xb   = (bf16*)alloc((size_t)M_*D_*2);
  bf16*  WfT  = (bf16*)alloc((size_t)NF*D_*2);     // [WpvT|WkT|WkvT|Wb1T], ld=1024
  bf16*  Wg1T = (bf16*)alloc((size_t)D_*2*D_*2);   // 1024 x 2048
  bf16*  WoT  = (bf16*)alloc((size_t)D_*D_*2);
  bf16*  PV   = (bf16*)alloc((size_t)M_*D_*2);
  bf16*  KV   = (bf16*)alloc((size_t)M_*D_*2);
  ushort* KP  = (ushort*)alloc((size_t)M_*D_*2);   // fp16 key phase
  ushort* ppH = (ushort*)alloc((size_t)L_*D_*2);   // fp16 pos phases
  bf16*  LNB  = (bf16*)alloc((size_t)M_*D_*2);
  float* gbuf  = (float*)alloc((size_t)M_*4);
  float* gcbuf = (float*)alloc((size_t)M_*4);
  float2* bwbuf= (float2*)alloc((size_t)M_*8);
  float* PS    = (float*)alloc((size_t)4*B_*CCH*D_*4);
  float* biasF = (float*)alloc((size_t)NF*4);
  // contiguous zero region: gacc | bwacc | zeros
  float* gacc  = (float*)alloc((size_t)M_*4);          // 65536 B
  float* bwacc = (float*)alloc((size_t)M_*2*4);        // 131072 B
  bf16*  zeros = (bf16*)alloc(256);
  int nzero = (M_ + 2*M_ + 64);

  k_zeroN<<<(nzero+255)/256,256,0,stream>>>(gacc, nzero);
  k_cvt<<<(M_*D_)/1024, 256, 0, stream>>>(x, xb);
  k_cvt_pp<<<(L_*D_)/1024, 256, 0, stream>>>(phases, ppH);

  dim3 tb(32,8);
  k_ctr<<<dim3(D_/32, D_/32), tb, 0, stream>>>(Wpv, WfT,                       D_, D_);
  k_ctr<<<dim3(D_/32, D_/32), tb, 0, stream>>>(Wk,  WfT + (size_t)1024*D_,     D_, D_);
  k_ctr<<<dim3(D_/32, D_/32), tb, 0, stream>>>(Wkv, WfT + (size_t)2048*D_,     D_, D_);
  k_ctr<<<dim3((D_/2)/32, D_/32), tb, 0, stream>>>(Wb1, WfT + (size_t)3072*D_, D_, D_/2);
  k_ctr<<<dim3(D_/32, 2*D_/32), tb, 0, stream>>>(Wg1, Wg1T, 2*D_, D_);
  k_ctr<<<dim3(D_/32, D_/32), tb, 0, stream>>>(Wo,  WoT,  D_, D_);
  k_pack_bias<<<NF/256,256,0,stream>>>(bpv, bk, bkv, bb1, biasF);

  // fused PV/KP/KV + bw-fold : x @ [Wpv|Wk|Wkv|Wb1]  (M x 3584 x 1024)
  k_gemm<4,false><<<dim3(NF/BN, M_/BM),512,0,stream>>>(
      xb, D_, WfT, D_, biasF, zeros, PV, KP, KV, nullptr, Wb2, nullptr, bwacc,
      nullptr, nullptr, NF, D_);
  // concat GEMM with gate-fold: gacc[row] += sum gelu(...)*Wg2  (M x 1024 x 2048)
  k_gemm<2,true><<<dim3(D_/BN, M_/BM),512,0,stream>>>(
      xb, D_, Wg1T, 2*D_, bg1, zeros, nullptr, nullptr, nullptr, Wg2, nullptr, gacc, nullptr,
      nullptr, nullptr, D_, 2*D_);
  // gate sigmoid + cumsum
  k_gscan<<<B_,1024,0,stream>>>(gacc, bg2, gbuf, gcbuf);
  // blend weights softmax
  k_finishbw<<<M_/256,256,0,stream>>>(bwacc, bb2, bwbuf);
  // chunked scans -> LN'd blended
  dim3 sg(CCH, B_);
  k_scan_partial<<<sg,256,0,stream>>>(PV, KV, KP, gbuf, ppH, PS);
  k_prefix<<<(4*B_*D_)/256,256,0,stream>>>(PS);
  k_scan_apply<<<sg,256,0,stream>>>(PV, KV, KP, gbuf, ppH, PS, gcbuf, bwbuf, ln_g, ln_b, LNB);
  // out = x + LN@Wo + bo   (fp32 out, fp32 resid)
  k_gemm<3,false><<<dim3(D_/BN, M_/BM),512,0,stream>>>(
      LNB, D_, WoT, D_, bo, zeros, nullptr, nullptr, nullptr, nullptr, nullptr, nullptr, nullptr,
      out, x, D_, D_);
}